// Round 7
// baseline (195.928 us; speedup 1.0000x reference)
//
#include <hip/hip_runtime.h>
#include <math.h>
#include <stdint.h>

typedef uint32_t u32; typedef uint64_t u64; typedef uint16_t u16; typedef int32_t i32;

#define BATCH 8
#define NA    261888      // anchors per batch = 16 segs * 16368
#define SEGS  16          // histcache blocks per batch
#define SEGCHUNK 16368    // elements per block
#define WCHUNK 4092       // elements per wave (4 waves/block)
#define SUBCAP 128        // cache slots per (block,wave) sub-segment
#define TOPK  6000        // PRE_NMS_LIMIT (fallback only)
#define PROP  1000        // PROPOSAL_COUNT
#define TOP1  1024        // fast-path window = Jacobi/mask width
#define SORTN 2048        // filtered candidate cap for rank-select
#define CACHEB 8192       // cache slots per batch (16 segs * 4 waves * 128)
#define FBMAX 16384       // fallback candidate capacity (~10.1K expected)
#define MW32  32          // u32 words per 1024-bit candidate bitmap
#define PSTATIC 0x3F7C0000u   // 0.984375f: start of coarse bin 4063; cache = {bits >= PSTATIC}

// ws layout — 2,787,456 B total (< round-2-proven 3,022,208; fill counter shows
// ws_size = 256 MiB but stay within proven bounds anyway). fbkeys aliases h1p
// (h1p dead after k_sortdec's merge; fb runs in k_nmsfb; stream-ordered).
#define OFF_H1P   0              // u16 h1p[8][16][4096]  = 1,048,576
#define OFF_FBK   0              // u64 fbkeys[8][16384]  = 1,048,576 (alias, fb only)
#define OFF_CACHE 1048576        // u64 cache[8][8192]    =   524,288
#define OFF_CNT   1572864        // u32 cnt[8][64]        =     2,048 (always fully written)
#define OFF_B1G1  1574912        // u32 [8][4] b1,g1,b6,status = 128
#define OFF_BOX   1575040        // float4 boxes[8][1024] =   131,072
#define OFF_AREA  1706112        // float areas[8][1024]  =    32,768
#define OFF_MASK  1738880        // u32 maskT[8][32][1024]= 1,048,576
#define WS_NEEDED 2787456

// ---------------- shared exact numerics -------------------------------------

// bit-faithful numpy fp32 decode (no FMA contraction; correctly-rounded exp)
__device__ __forceinline__ void decode_box(const float4 an, const float4 dl,
                                           float4& bx, float& ar) {
    float d0 = __fmul_rn(dl.x, 0.1f), d1 = __fmul_rn(dl.y, 0.1f);
    float d2 = __fmul_rn(dl.z, 0.2f), d3 = __fmul_rn(dl.w, 0.2f);
    float h = __fsub_rn(an.z, an.x), w = __fsub_rn(an.w, an.y);
    float cy = __fadd_rn(__fadd_rn(an.x, __fmul_rn(0.5f, h)), __fmul_rn(d0, h));
    float cx = __fadd_rn(__fadd_rn(an.y, __fmul_rn(0.5f, w)), __fmul_rn(d1, w));
    float h2 = __fmul_rn(h, (float)exp((double)d2));
    float w2 = __fmul_rn(w, (float)exp((double)d3));
    float y1 = __fsub_rn(cy, __fmul_rn(0.5f, h2));
    float x1 = __fsub_rn(cx, __fmul_rn(0.5f, w2));
    float y2 = __fadd_rn(y1, h2);
    float x2 = __fadd_rn(x1, w2);
    y1 = fminf(fmaxf(y1, 0.f), 1.f); x1 = fminf(fmaxf(x1, 0.f), 1.f);
    y2 = fminf(fmaxf(y2, 0.f), 1.f); x2 = fminf(fmaxf(x2, 0.f), 1.f);
    bx = make_float4(y1, x1, y2, x2);
    ar = __fmul_rn(__fsub_rn(y2, y1), __fsub_rn(x2, x1));
}

// suppress(i,j) <=> RN(inter/union) > 0.7f <=> inter >= ((double)0.7f+2^-25)*union
// (product <= 49 significant bits -> double compare EXACT incl. tie-to-even midpoint)
__device__ __forceinline__ bool sup_pred(const float4 bi, const float ai,
                                         const float4 bj, const float aj) {
    const double tmid = (double)0.7f + 0x1p-25;
    float yy1 = fmaxf(bi.x, bj.x), xx1 = fmaxf(bi.y, bj.y);
    float yy2 = fminf(bi.z, bj.z), xx2 = fminf(bi.w, bj.w);
    float ih = fmaxf(__fsub_rn(yy2, yy1), 0.f);
    float iw = fmaxf(__fsub_rn(xx2, xx1), 0.f);
    float inter = __fmul_rn(ih, iw);
    float uni = __fsub_rn(__fadd_rn(ai, aj), inter);
    return (uni > 0.f) && ((double)inter >= tmid * (double)uni);
}

// ---------------- phase 1: single probs pass ---------------------------------
// Partial coarse histogram (bits[31:18], u16) AND cache of all candidates with
// bits >= PSTATIC (mean 4092/batch, sigma ~63). Per-wave ballot-prefix slot
// allocation into a fixed 128-slot sub-segment: no global atomics, no barriers
// for allocation, no memset dependency (cnt always fully written).
__global__ __launch_bounds__(256) void k_histcache(const float2* __restrict__ p2,
                                                   u16* __restrict__ h1p,
                                                   u64* __restrict__ cache,
                                                   u32* __restrict__ cnt) {
    __shared__ u32 h[4096];
    const int b = blockIdx.y, seg = blockIdx.x;
    const int wave = threadIdx.x >> 6, lane = threadIdx.x & 63;
    for (int i = threadIdx.x; i < 4096; i += 256) h[i] = 0;
    __syncthreads();
    const u64 lmask = (1ull << lane) - 1ull;
    const size_t ebase = (size_t)b * NA + seg * SEGCHUNK + wave * WCHUNK;
    u64* cseg = cache + (size_t)b * CACHEB + (seg * 4 + wave) * SUBCAP;
    u32 wOff = 0;
    for (int it = 0; it < 64; ++it) {                 // 63 full + 1 partial (60 lanes)
        int e = it * 64 + lane;
        bool ok = e < WCHUNK;
        u32 bits = 0;
        if (ok) bits = __float_as_uint(p2[ebase + e].y);
        if (ok) atomicAdd(&h[bits >> 18], 1u);        // LDS atomic; scores in [0,1)
        bool p = ok && (bits >= PSTATIC);
        u64 wmask = __ballot(p);
        if (p) {
            u32 slot = wOff + (u32)__popcll(wmask & lmask);
            if (slot < SUBCAP) {
                u32 a = (u32)(seg * SEGCHUNK + wave * WCHUNK + e);
                cseg[slot] = ((u64)(~bits) << 32) | (u64)a;
            }
        }
        wOff += (u32)__popcll(wmask);
    }
    if (lane == 0) cnt[b * 64 + seg * 4 + wave] = wOff;   // true count (>SUBCAP -> fb)
    __syncthreads();
    u16* dst = h1p + ((size_t)b * SEGS + seg) * 4096;
    for (int i = threadIdx.x; i < 4096; i += 256) dst[i] = (u16)h[i];
}

// ---------------- phase 2: select + exact rank + decode (fused) --------------
// merge partials -> (b1,g1) rank-1024 coarse, b6 rank-6000 coarse (fb);
// rebuild fine histogram (bits[17:6] within b1) FROM THE CACHE (33 KB, not
// another 16.7 MB probs pass); refine to P with count(bits>=P) in [1024,~1030];
// filter; direct rank-select (unique u64 keys (~score,idx) => exact lax.top_k
// order); decode sorted top-1024.
__global__ __launch_bounds__(1024) void k_sortdec(const u16* __restrict__ h1p,
                                                  const u64* __restrict__ cache,
                                                  const u32* __restrict__ cnt,
                                                  const float4* __restrict__ anchors,
                                                  const float4* __restrict__ bbox,
                                                  u32* __restrict__ b1g1,
                                                  float4* __restrict__ boxes,
                                                  float* __restrict__ areas) {
    __shared__ u32 merged[4096];     // coarse hist -> fine hist -> ridx[1024]
    __shared__ u32 ps[256];
    __shared__ u64 s[SORTN];
    __shared__ u32 scnt[64];
    __shared__ u32 sb1, sg1, sb6, sP, sm, stat;
    const int b = blockIdx.x;
    const int tid = threadIdx.x;
    if (tid == 0) { stat = 1u; sm = 0; }
    // ---- merge 16 partial coarse histograms ----
    {
        u32 m0 = 0, m1 = 0, m2 = 0, m3 = 0;
        for (int blk = 0; blk < SEGS; ++blk) {
            const ushort4 v = ((const ushort4*)(h1p + ((size_t)b * SEGS + blk) * 4096))[tid];
            m0 += v.x; m1 += v.y; m2 += v.z; m3 += v.w;
        }
        merged[tid * 4] = m0; merged[tid * 4 + 1] = m1;
        merged[tid * 4 + 2] = m2; merged[tid * 4 + 3] = m3;
    }
    if (tid < 64) {                                   // sub-segment counts (+overflow check)
        u32 raw = cnt[b * 64 + tid];
        if (raw > SUBCAP) { scnt[tid] = SUBCAP; stat = 0u; }
        else scnt[tid] = raw;
    }
    __syncthreads();
    if (tid < 256) {
        u32 su = 0;
        for (int k = 0; k < 16; ++k) su += merged[tid * 16 + k];
        ps[tid] = su;
    }
    __syncthreads();
    if (tid == 0) {
        {   // coarse rank-TOP1 bin
            u32 acc = 0; int seg = 0;
            for (int t = 255; t >= 0; --t) { if (acc + ps[t] >= TOP1) { seg = t; break; } acc += ps[t]; }
            int b1 = seg * 16; u32 g1 = acc;
            for (int k = 15; k >= 0; --k) {
                u32 c = merged[seg * 16 + k];
                if (g1 + c >= TOP1) { b1 = seg * 16 + k; break; }
                g1 += c;
            }
            sb1 = (u32)b1; sg1 = g1;
            if (((u32)b1 << 18) < PSTATIC) stat = 0u;   // cache doesn't cover bin b1 -> fb
        }
        {   // coarse rank-TOPK bin (fallback threshold; always valid)
            u32 acc = 0; int seg = 0;
            for (int t = 255; t >= 0; --t) { if (acc + ps[t] >= TOPK) { seg = t; break; } acc += ps[t]; }
            int b6 = seg * 16; u32 g6 = acc;
            for (int k = 15; k >= 0; --k) {
                u32 c = merged[seg * 16 + k];
                if (g6 + c >= TOPK) { b6 = seg * 16 + k; break; }
                g6 += c;
            }
            sb6 = (u32)b6;
        }
    }
    __syncthreads();
    const u32 b1 = sb1, g1 = sg1;
    // ---- fine histogram (bits[17:6] within bin b1) from the cache ----
    for (int i = tid; i < 4096; i += 1024) merged[i] = 0;
    __syncthreads();
    for (int t = tid; t < CACHEB; t += 1024) {
        int sub = t >> 7, off = t & (SUBCAP - 1);
        if (off < (int)scnt[sub]) {
            u32 bits = ~((u32)(cache[(size_t)b * CACHEB + t] >> 32));
            if ((bits >> 18) == b1) atomicAdd(&merged[(bits >> 6) & 0xFFFu], 1u);
        }
    }
    __syncthreads();
    if (tid < 256) {
        u32 su = 0;
        for (int k = 0; k < 16; ++k) su += merged[tid * 16 + k];
        ps[tid] = su;
    }
    __syncthreads();
    if (tid == 0) {                                   // refine to rank-TOP1 threshold
        u32 acc = g1; int seg = 0;
        for (int t = 255; t >= 0; --t) { if (acc + ps[t] >= TOP1) { seg = t; break; } acc += ps[t]; }
        int b2 = seg * 16; u32 g = acc;
        for (int k = 15; k >= 0; --k) {
            u32 c = merged[seg * 16 + k];
            if (g + c >= TOP1) { b2 = seg * 16 + k; break; }
            g += c;
        }
        sP = (b1 << 18) | ((u32)b2 << 6);             // count(bits>=P) in [1024, ~1030]
    }
    __syncthreads();
    // ---- filter cache by P into dense s[] (fine hist no longer needed) ----
    const u64 thrKey = ((u64)(~sP) << 32) | 0xFFFFFFFFull;   // key<=thrKey <=> bits>=P
    for (int i = tid; i < SORTN; i += 1024) s[i] = ~0ull;
    if (tid < TOP1) merged[tid] = 0xFFFFFFFFu;        // ridx sentinel
    __syncthreads();
    for (int t = tid; t < CACHEB; t += 1024) {
        int sub = t >> 7, off = t & (SUBCAP - 1);
        if (off < (int)scnt[sub]) {
            u64 key = cache[(size_t)b * CACHEB + t];
            if (key <= thrKey) {
                u32 slot = atomicAdd(&sm, 1u);
                if (slot < SORTN) s[slot] = key;
            }
        }
    }
    __syncthreads();
    if (tid == 0 && (sm < TOP1 || sm > SORTN)) stat = 0u;
    int mm = (int)sm; if (mm > SORTN) mm = SORTN;
    // ---- direct rank-select: rank = #{keys < key} (keys unique) ----
    for (int sidx = tid; sidx < mm; sidx += 1024) {
        u64 k0 = s[sidx];
        u32 r = 0;
        for (int j = 0; j < mm; ++j) r += (s[j] < k0) ? 1u : 0u;   // LDS broadcast
        if (r < TOP1) merged[r] = (u32)k0;            // anchor index at exact rank r
    }
    __syncthreads();
    // ---- decode sorted top-1024 ----
    u32 idx = merged[tid];
    float4 bx; float ar;
    if (idx == 0xFFFFFFFFu) { bx = make_float4(-5.f, -5.f, -5.f, -5.f); ar = 0.f; }
    else decode_box(anchors[(size_t)b * NA + idx], bbox[(size_t)b * NA + idx], bx, ar);
    boxes[b * TOP1 + tid] = bx;
    areas[b * TOP1 + tid] = ar;
    if (tid == 0) {
        b1g1[b * 4] = b1; b1g1[b * 4 + 1] = g1;
        b1g1[b * 4 + 2] = sb6; b1g1[b * 4 + 3] = stat;
    }
}

// ---------------- phase 3: NMS ----------------------------------------------

// one wave per mask row; bi in registers, bj coalesced from global (L1-resident
// 16 KB/batch); no LDS, no __syncthreads, 16 independent chunks for ILP.
// maskT[b][w][i] = word w (candidates 32w..32w+31) of row i (TRANSPOSED)
__global__ __launch_bounds__(256) void k_mask(const float4* __restrict__ boxes,
                                              const float* __restrict__ areas,
                                              u32* __restrict__ mt_all) {
    const int b = blockIdx.y;
    const int wave = threadIdx.x >> 6, lane = threadIdx.x & 63;
    const int i = blockIdx.x * 4 + wave;          // row 0..1023 (grid.x = 256)
    u32* mt = mt_all + (size_t)b * MW32 * TOP1;
    float4 bi = boxes[b * TOP1 + i];
    float  ai = areas[b * TOP1 + i];
    #pragma unroll
    for (int c = 0; c < 16; ++c) {
        float4 bj = boxes[b * TOP1 + c * 64 + lane];
        float  aj = areas[b * TOP1 + c * 64 + lane];
        u64 word = __ballot(sup_pred(bi, ai, bj, aj));
        if (lane == 0) {
            mt[(2 * c) * TOP1 + i]     = (u32)word;
            mt[(2 * c + 1) * TOP1 + i] = (u32)(word >> 32);
        }
    }
}

// Jacobi fixed-point NMS (unique fixed point == greedy result) + inline exact
// fallback (expected never taken: runs only if status!=ok, non-convergence, or
// accepts < PROP within the 1024 window; redoes reference computation exactly)
__global__ __launch_bounds__(1024) void k_nmsfb(const u32* __restrict__ mt_all,
                                                const float4* __restrict__ boxes,
                                                const float2* __restrict__ p2,
                                                const float4* __restrict__ bbox,
                                                const float4* __restrict__ anchors,
                                                const u32* __restrict__ b1g1,
                                                u64* __restrict__ fbkeys,
                                                float4* __restrict__ out) {
    __shared__ u32 valid[MW32];
    __shared__ u32 wpre[MW32 + 1];
    __shared__ u32 chg;
    __shared__ float4 abox[PROP];
    __shared__ float  aar[PROP];
    __shared__ u32 nsh;
    const int b = blockIdx.x;
    const int i = threadIdx.x;                 // candidate 0..1023
    const int wv = i >> 6, lane = i & 63;
    const int wi = i >> 5;
    const u32* mt = mt_all + (size_t)b * MW32 * TOP1;
    u32 row[MW32];                             // row i, masked to j<i (coalesced loads)
    #pragma unroll
    for (int w = 0; w < MW32; ++w) row[w] = 0;
    for (int w = 0; w < wi; ++w) row[w] = mt[w * TOP1 + i];
    row[wi] = mt[wi * TOP1 + i] & ((1u << (i & 31)) - 1u);
    if (i < MW32) valid[i] = 0xFFFFFFFFu;
    bool conv = false;
    for (int it = 0; it < 48; ++it) {
        __syncthreads();
        if (i == 0) chg = 0;
        u32 sup = 0;
        #pragma unroll
        for (int w = 0; w < MW32; ++w) sup |= valid[w] & row[w];
        u64 nb = __ballot(sup == 0u);
        __syncthreads();
        if (lane == 0) {
            u32 lo = (u32)nb, hi = (u32)(nb >> 32);
            if (valid[2 * wv] != lo)     { valid[2 * wv] = lo;     atomicOr(&chg, 1u); }
            if (valid[2 * wv + 1] != hi) { valid[2 * wv + 1] = hi; atomicOr(&chg, 1u); }
        }
        __syncthreads();
        if (chg == 0u) { conv = true; break; }
    }
    __syncthreads();
    if (i == 0) {
        u32 r = 0;
        for (int w = 0; w < MW32; ++w) { wpre[w] = r; r += __popc(valid[w]); }
        wpre[MW32] = r;
    }
    __syncthreads();
    u32 V = wpre[MW32];
    if (conv && V >= PROP && b1g1[b * 4 + 3] != 0u) {   // fast path (expected always)
        u32 vw = valid[wi];
        bool isv = ((vw >> (i & 31)) & 1u) != 0;
        u32 rank = wpre[wi] + __popc(vw & ((1u << (i & 31)) - 1u));
        if (isv && rank < PROP) out[b * PROP + rank] = boxes[b * TOP1 + i];
        return;                                         // V>=PROP: all PROP ranks written
    }
    // ---- exact fallback: redo reference computation from raw inputs ----
    if (i == 0) nsh = 0;
    __syncthreads();
    u32 P6 = b1g1[b * 4 + 2] << 18;            // coarse rank-6000 threshold (always valid)
    for (int a = i; a < NA; a += 1024) {
        u32 bits = __float_as_uint(p2[(size_t)b * NA + a].y);
        if (bits >= P6) {
            u32 p = atomicAdd(&nsh, 1u);
            if (p < FBMAX) fbkeys[(size_t)b * FBMAX + p] = ((u64)(~bits) << 32) | (u64)a;
        }
    }
    __syncthreads();
    u32 n = nsh; if (n > FBMAX) n = FBMAX;     // ~10.1K expected; overflow impossible
    volatile u64* vk = (volatile u64*)(fbkeys + (size_t)b * FBMAX);
    for (int i2 = (int)n + i; i2 < FBMAX; i2 += 1024) vk[i2] = ~0ull;
    __syncthreads();
    for (int k = 2; k <= FBMAX; k <<= 1) {     // global-memory bitonic, exact order
        for (int j = k >> 1; j > 0; j >>= 1) {
            for (int p = i; p < FBMAX / 2; p += 1024) {
                int ii = ((p & ~(j - 1)) << 1) | (p & (j - 1));
                int l = ii | j;
                u64 a = vk[ii], c = vk[l];
                bool up = ((ii & k) == 0);
                if ((a > c) == up) { vk[ii] = c; vk[l] = a; }
            }
            __syncthreads();
        }
    }
    int acc_n = 0;
    int limit = (int)n < TOPK ? (int)n : TOPK;
    for (int t = 0; t < limit && acc_n < PROP; ++t) {
        u32 idx = (u32)vk[t];
        float4 bi2; float ai2;
        decode_box(anchors[(size_t)b * NA + idx], bbox[(size_t)b * NA + idx], bi2, ai2);
        int pred = 0;
        if (i < acc_n) pred = sup_pred(bi2, ai2, abox[i], aar[i]) ? 1 : 0;
        int any = __syncthreads_or(pred);
        if (!any) {
            if (i == 0) {
                abox[acc_n] = bi2; aar[acc_n] = ai2;
                out[b * PROP + acc_n] = bi2;
            }
            ++acc_n;
            __syncthreads();
        }
    }
    for (int t = acc_n + i; t < PROP; t += 1024)
        out[b * PROP + t] = make_float4(0.f, 0.f, 0.f, 0.f);
}

// ---------------- launch ----------------------------------------------------

extern "C" void kernel_launch(void* const* d_in, const int* in_sizes, int n_in,
                              void* d_out, int out_size, void* d_ws, size_t ws_size,
                              hipStream_t stream) {
    (void)in_sizes; (void)n_in; (void)out_size;
    if (ws_size < (size_t)WS_NEEDED) return;   // ws_size constant per process -> same work every call
    const float2* p2      = (const float2*)d_in[0];
    const float4* bbox    = (const float4*)d_in[1];
    const float4* anchors = (const float4*)d_in[2];
    float4* out = (float4*)d_out;

    char* ws = (char*)d_ws;
    u16* h1p     = (u16*)(ws + OFF_H1P);
    u64* fbkeys  = (u64*)(ws + OFF_FBK);       // aliases h1p (dead by nmsfb time)
    u64* cache   = (u64*)(ws + OFF_CACHE);
    u32* cnt     = (u32*)(ws + OFF_CNT);
    u32* b1g1    = (u32*)(ws + OFF_B1G1);
    float4* boxes= (float4*)(ws + OFF_BOX);
    float* areas = (float*)(ws + OFF_AREA);
    u32* maskT   = (u32*)(ws + OFF_MASK);

    dim3 ghc(SEGS, BATCH), gmask(TOP1 / 4, BATCH);
    k_histcache<<<ghc,   256, 0, stream>>>(p2, h1p, cache, cnt);
    k_sortdec  <<<BATCH, 1024, 0, stream>>>(h1p, cache, cnt, anchors, bbox, b1g1, boxes, areas);
    k_mask     <<<gmask, 256, 0, stream>>>(boxes, areas, maskT);
    k_nmsfb    <<<BATCH, 1024, 0, stream>>>(maskT, boxes, p2, bbox, anchors, b1g1, fbkeys, out);
}

// Round 8
// 164.269 us; speedup vs baseline: 1.1927x; 1.1927x over previous
//
#include <hip/hip_runtime.h>
#include <math.h>
#include <stdint.h>

typedef uint32_t u32; typedef uint64_t u64; typedef uint16_t u16; typedef int32_t i32;

#define BATCH 8
#define NA    261888      // anchors per batch = 16 segs * 16368
#define SEGS  16          // histcache blocks per batch
#define SEGCHUNK 16368    // elements per block
#define WCHUNK 4092       // elements per wave (4 waves/block)
#define SUBCAP 128        // cache slots per (block,wave) sub-segment
#define TOPK  6000        // PRE_NMS_LIMIT (fallback only)
#define PROP  1000        // PROPOSAL_COUNT
#define TOP1  1024        // fast-path window = Jacobi/mask width
#define SORTN 2048        // bitonic size for top-1024 refinement
#define CACHEB 8192       // cache slots per batch (16 segs * 4 waves * 128)
#define FBMAX 16384       // fallback candidate capacity (~6.1K expected)
#define MW32  32          // u32 words per 1024-bit candidate bitmap
#define PSTATIC 0x3F7C0000u   // 0.984375f; cache = {bits >= PSTATIC}, mean 4092/batch
                              // (low 18 bits zero -> (bits>>6)&0xFFF monotone over range)

// ws layout — 2,787,456 B total (well under 256 MiB ws; stays under all proven
// bounds). fbkeys region is fb-only (never touched on the fast path).
#define OFF_FBK   0              // u64 fbkeys[8][16384]  = 1,048,576 (fb only)
#define OFF_CACHE 1048576        // u64 cache[8][8192]    =   524,288
#define OFF_CNT   1572864        // u32 cnt[8][64]        =     2,048 (always fully written)
#define OFF_STAT  1574912        // u32 stat[8] (+pad)    =       128
#define OFF_BOX   1575040        // float4 boxes[8][1024] =   131,072
#define OFF_AREA  1706112        // float areas[8][1024]  =    32,768
#define OFF_MASK  1738880        // u32 maskT[8][32][1024]= 1,048,576
#define WS_NEEDED 2787456

// ---------------- shared exact numerics -------------------------------------

// bit-faithful numpy fp32 decode (no FMA contraction; correctly-rounded exp)
__device__ __forceinline__ void decode_box(const float4 an, const float4 dl,
                                           float4& bx, float& ar) {
    float d0 = __fmul_rn(dl.x, 0.1f), d1 = __fmul_rn(dl.y, 0.1f);
    float d2 = __fmul_rn(dl.z, 0.2f), d3 = __fmul_rn(dl.w, 0.2f);
    float h = __fsub_rn(an.z, an.x), w = __fsub_rn(an.w, an.y);
    float cy = __fadd_rn(__fadd_rn(an.x, __fmul_rn(0.5f, h)), __fmul_rn(d0, h));
    float cx = __fadd_rn(__fadd_rn(an.y, __fmul_rn(0.5f, w)), __fmul_rn(d1, w));
    float h2 = __fmul_rn(h, (float)exp((double)d2));
    float w2 = __fmul_rn(w, (float)exp((double)d3));
    float y1 = __fsub_rn(cy, __fmul_rn(0.5f, h2));
    float x1 = __fsub_rn(cx, __fmul_rn(0.5f, w2));
    float y2 = __fadd_rn(y1, h2);
    float x2 = __fadd_rn(x1, w2);
    y1 = fminf(fmaxf(y1, 0.f), 1.f); x1 = fminf(fmaxf(x1, 0.f), 1.f);
    y2 = fminf(fmaxf(y2, 0.f), 1.f); x2 = fminf(fmaxf(x2, 0.f), 1.f);
    bx = make_float4(y1, x1, y2, x2);
    ar = __fmul_rn(__fsub_rn(y2, y1), __fsub_rn(x2, x1));
}

// suppress(i,j) <=> RN(inter/union) > 0.7f <=> inter >= ((double)0.7f+2^-25)*union
// (product <= 49 significant bits -> double compare EXACT incl. tie-to-even midpoint)
__device__ __forceinline__ bool sup_pred(const float4 bi, const float ai,
                                         const float4 bj, const float aj) {
    const double tmid = (double)0.7f + 0x1p-25;
    float yy1 = fmaxf(bi.x, bj.x), xx1 = fmaxf(bi.y, bj.y);
    float yy2 = fminf(bi.z, bj.z), xx2 = fminf(bi.w, bj.w);
    float ih = fmaxf(__fsub_rn(yy2, yy1), 0.f);
    float iw = fmaxf(__fsub_rn(xx2, xx1), 0.f);
    float inter = __fmul_rn(ih, iw);
    float uni = __fsub_rn(__fadd_rn(ai, aj), inter);
    return (uni > 0.f) && ((double)inter >= tmid * (double)uni);
}

// ---------------- phase 1: single probs pass (pure stream) -------------------
// Cache all candidates with bits >= PSTATIC via per-wave ballot-prefix slot
// allocation into fixed 128-slot sub-segments. No LDS, no barriers, no global
// atomics, no histogram. float4 loads (2 anchors/lane) halve iteration count.
__global__ __launch_bounds__(256) void k_histcache(const float4* __restrict__ p4,
                                                   u64* __restrict__ cache,
                                                   u32* __restrict__ cnt) {
    const int b = blockIdx.y, seg = blockIdx.x;
    const int wave = threadIdx.x >> 6, lane = threadIdx.x & 63;
    const u64 lmask = (1ull << lane) - 1ull;
    const size_t fbase = ((size_t)b * NA + seg * SEGCHUNK + wave * WCHUNK) >> 1;
    const u32 abase = (u32)(seg * SEGCHUNK + wave * WCHUNK);
    u64* cseg = cache + (size_t)b * CACHEB + (seg * 4 + wave) * SUBCAP;
    u32 wOff = 0;
    #pragma unroll 4
    for (int it = 0; it < 32; ++it) {          // 2046 float4/wave: 31 full + 62 lanes
        int f = it * 64 + lane;
        bool ok = f < (WCHUNK / 2);
        u32 bitsA = 0, bitsB = 0;
        if (ok) {
            float4 v = p4[fbase + f];
            bitsA = __float_as_uint(v.y);      // anchor 2f score
            bitsB = __float_as_uint(v.w);      // anchor 2f+1 score
        }
        bool pA = ok && bitsA >= PSTATIC;
        bool pB = ok && bitsB >= PSTATIC;
        u64 mA = __ballot(pA);
        u64 mB = __ballot(pB);
        u32 cA = (u32)__popcll(mA);
        if (pA) {
            u32 slot = wOff + (u32)__popcll(mA & lmask);
            if (slot < SUBCAP) cseg[slot] = ((u64)(~bitsA) << 32) | (u64)(abase + 2 * f);
        }
        if (pB) {
            u32 slot = wOff + cA + (u32)__popcll(mB & lmask);
            if (slot < SUBCAP) cseg[slot] = ((u64)(~bitsB) << 32) | (u64)(abase + 2 * f + 1);
        }
        wOff += cA + (u32)__popcll(mB);
    }
    if (lane == 0) cnt[b * 64 + seg * 4 + wave] = wOff;   // true count (>SUBCAP -> fb)
}

// ---------------- phase 2: rank-1024 threshold + bitonic + decode ------------
// Fine histogram (4096 bins over the cached ulp range) built FROM THE CACHE;
// refine threshold P with count(bits>=P) in [1024,~1026]; filter; bitonic-sort
// 2048 (exact lax.top_k order: key=(~score_bits,index)); decode sorted top-1024.
__global__ __launch_bounds__(1024) void k_sortdec(const u64* __restrict__ cache,
                                                  const u32* __restrict__ cnt,
                                                  const float4* __restrict__ anchors,
                                                  const float4* __restrict__ bbox,
                                                  u32* __restrict__ stat_g,
                                                  float4* __restrict__ boxes,
                                                  float* __restrict__ areas) {
    __shared__ u32 hist[4096];
    __shared__ u32 ps[256];
    __shared__ u64 s[SORTN];
    __shared__ u32 scnt[64];
    __shared__ u32 sP, sm, stat;
    const int b = blockIdx.x;
    const int tid = threadIdx.x;
    if (tid == 0) { stat = 1u; sm = 0; }
    for (int i = tid; i < 4096; i += 1024) hist[i] = 0;
    for (int i = tid; i < SORTN; i += 1024) s[i] = ~0ull;
    __syncthreads();
    if (tid < 64) {
        u32 raw = cnt[b * 64 + tid];
        scnt[tid] = raw > SUBCAP ? SUBCAP : raw;
        if (raw > SUBCAP) stat = 0u;           // cache dropped elements -> fb
    }
    __syncthreads();
    // fine histogram from cache (all cached bits >= PSTATIC; mapping monotone)
    for (int t = tid; t < CACHEB; t += 1024) {
        int sub = t >> 7, off = t & (SUBCAP - 1);
        if (off < (int)scnt[sub]) {
            u32 bits = ~((u32)(cache[(size_t)b * CACHEB + t] >> 32));
            atomicAdd(&hist[(bits >> 6) & 0xFFFu], 1u);
        }
    }
    __syncthreads();
    if (tid < 256) {
        u32 su = 0;
        for (int k = 0; k < 16; ++k) su += hist[tid * 16 + k];
        ps[tid] = su;
    }
    __syncthreads();
    if (tid == 0) {
        u32 acc = 0; int seg = -1;
        for (int t = 255; t >= 0; --t) {
            if (acc + ps[t] >= TOP1) { seg = t; break; }
            acc += ps[t];
        }
        if (seg < 0) { stat = 0u; sP = PSTATIC; }   // M < 1024 -> fb
        else {
            int bin = seg * 16; u32 g = acc;
            for (int k = 15; k >= 0; --k) {
                u32 c = hist[seg * 16 + k];
                if (g + c >= TOP1) { bin = seg * 16 + k; break; }
                g += c;
            }
            sP = PSTATIC + ((u32)bin << 6);     // count(bits>=sP) in [1024, 1023+occ]
        }
    }
    __syncthreads();
    const u64 thrKey = ((u64)(~sP) << 32) | 0xFFFFFFFFull;   // key<=thrKey <=> bits>=sP
    for (int t = tid; t < CACHEB; t += 1024) {
        int sub = t >> 7, off = t & (SUBCAP - 1);
        if (off < (int)scnt[sub]) {
            u64 key = cache[(size_t)b * CACHEB + t];
            if (key <= thrKey) {
                u32 slot = atomicAdd(&sm, 1u);
                if (slot < SORTN) s[slot] = key;
            }
        }
    }
    __syncthreads();
    if (tid == 0 && (sm < TOP1 || sm > SORTN)) stat = 0u;
    // bitonic sort 2048 (ascending; pads ~0ull sink to the bottom)
    for (int k = 2; k <= SORTN; k <<= 1) {
        for (int j = k >> 1; j > 0; j >>= 1) {
            int p = tid;                        // exactly SORTN/2 pairs
            int i = ((p & ~(j - 1)) << 1) | (p & (j - 1));
            int l = i | j;
            u64 a = s[i], c = s[l];
            bool up = ((i & k) == 0);
            if ((a > c) == up) { s[i] = c; s[l] = a; }
            __syncthreads();
        }
    }
    // decode sorted top-1024
    u32 idx = (u32)s[tid];
    float4 bx; float ar;
    if (idx == 0xFFFFFFFFu) { bx = make_float4(-5.f, -5.f, -5.f, -5.f); ar = 0.f; }
    else decode_box(anchors[(size_t)b * NA + idx], bbox[(size_t)b * NA + idx], bx, ar);
    boxes[b * TOP1 + tid] = bx;
    areas[b * TOP1 + tid] = ar;
    if (tid == 0) stat_g[b] = stat;
}

// ---------------- phase 3: NMS ----------------------------------------------

// one wave per mask row; bi in registers, bj coalesced from global (L1-resident
// 16 KB/batch); no LDS, no __syncthreads, 16 independent chunks for ILP.
// maskT[b][w][i] = word w (candidates 32w..32w+31) of row i (TRANSPOSED)
__global__ __launch_bounds__(256) void k_mask(const float4* __restrict__ boxes,
                                              const float* __restrict__ areas,
                                              u32* __restrict__ mt_all) {
    const int b = blockIdx.y;
    const int wave = threadIdx.x >> 6, lane = threadIdx.x & 63;
    const int i = blockIdx.x * 4 + wave;          // row 0..1023 (grid.x = 256)
    u32* mt = mt_all + (size_t)b * MW32 * TOP1;
    float4 bi = boxes[b * TOP1 + i];
    float  ai = areas[b * TOP1 + i];
    #pragma unroll
    for (int c = 0; c < 16; ++c) {
        float4 bj = boxes[b * TOP1 + c * 64 + lane];
        float  aj = areas[b * TOP1 + c * 64 + lane];
        u64 word = __ballot(sup_pred(bi, ai, bj, aj));
        if (lane == 0) {
            mt[(2 * c) * TOP1 + i]     = (u32)word;
            mt[(2 * c + 1) * TOP1 + i] = (u32)(word >> 32);
        }
    }
}

// Jacobi fixed-point NMS (unique fixed point == greedy result) + inline exact
// self-contained fallback (expected never taken: runs only on status!=ok,
// non-convergence, or accepts < PROP; redoes the reference computation exactly
// from raw inputs, including its own rank-6000 threshold).
__global__ __launch_bounds__(1024) void k_nmsfb(const u32* __restrict__ mt_all,
                                                const float4* __restrict__ boxes,
                                                const float2* __restrict__ p2,
                                                const float4* __restrict__ bbox,
                                                const float4* __restrict__ anchors,
                                                const u32* __restrict__ stat_g,
                                                u64* __restrict__ fbkeys,
                                                float4* __restrict__ out) {
    __shared__ u32 valid[MW32];
    __shared__ u32 wpre[MW32 + 1];
    __shared__ u32 chg;
    const int b = blockIdx.x;
    const int i = threadIdx.x;                 // candidate 0..1023
    const int wv = i >> 6, lane = i & 63;
    const int wi = i >> 5;
    const u32* mt = mt_all + (size_t)b * MW32 * TOP1;
    u32 row[MW32];                             // row i, masked to j<i (coalesced loads)
    #pragma unroll
    for (int w = 0; w < MW32; ++w) row[w] = 0;
    for (int w = 0; w < wi; ++w) row[w] = mt[w * TOP1 + i];
    row[wi] = mt[wi * TOP1 + i] & ((1u << (i & 31)) - 1u);
    if (i < MW32) valid[i] = 0xFFFFFFFFu;
    bool conv = false;
    for (int it = 0; it < 48; ++it) {
        __syncthreads();
        if (i == 0) chg = 0;
        u32 sup = 0;
        #pragma unroll
        for (int w = 0; w < MW32; ++w) sup |= valid[w] & row[w];
        u64 nb = __ballot(sup == 0u);
        __syncthreads();
        if (lane == 0) {
            u32 lo = (u32)nb, hi = (u32)(nb >> 32);
            if (valid[2 * wv] != lo)     { valid[2 * wv] = lo;     atomicOr(&chg, 1u); }
            if (valid[2 * wv + 1] != hi) { valid[2 * wv + 1] = hi; atomicOr(&chg, 1u); }
        }
        __syncthreads();
        if (chg == 0u) { conv = true; break; }
    }
    __syncthreads();
    if (i == 0) {
        u32 r = 0;
        for (int w = 0; w < MW32; ++w) { wpre[w] = r; r += __popc(valid[w]); }
        wpre[MW32] = r;
    }
    __syncthreads();
    u32 V = wpre[MW32];
    if (conv && V >= PROP && stat_g[b] != 0u) {   // fast path (expected always)
        u32 vw = valid[wi];
        bool isv = ((vw >> (i & 31)) & 1u) != 0;
        u32 rank = wpre[wi] + __popc(vw & ((1u << (i & 31)) - 1u));
        if (isv && rank < PROP) out[b * PROP + rank] = boxes[b * TOP1 + i];
        return;                                   // V>=PROP: all PROP ranks written
    }
    // ---- exact fallback: self-contained redo of the reference computation ----
    __shared__ float4 abox[PROP];
    __shared__ float  aar[PROP];
    __shared__ u32 fh[4096];
    __shared__ u32 fps[256];
    __shared__ u32 nsh, sP6;
    if (i == 0) nsh = 0;
    for (int z = i; z < 4096; z += 1024) fh[z] = 0;
    __syncthreads();
    for (int a = i; a < NA; a += 1024) {          // own coarse hist (bits[31:18])
        u32 bits = __float_as_uint(p2[(size_t)b * NA + a].y);
        atomicAdd(&fh[bits >> 18], 1u);
    }
    __syncthreads();
    if (i < 256) {
        u32 su = 0;
        for (int k = 0; k < 16; ++k) su += fh[i * 16 + k];
        fps[i] = su;
    }
    __syncthreads();
    if (i == 0) {                                 // rank-TOPK coarse bin -> P6
        u32 acc = 0; int seg = 0;
        for (int t = 255; t >= 0; --t) { if (acc + fps[t] >= TOPK) { seg = t; break; } acc += fps[t]; }
        int b6 = seg * 16; u32 g6 = acc;
        for (int k = 15; k >= 0; --k) {
            u32 c = fh[seg * 16 + k];
            if (g6 + c >= TOPK) { b6 = seg * 16 + k; break; }
            g6 += c;
        }
        sP6 = (u32)b6 << 18;                      // count(bits>=sP6) in [6000,~6070]
    }
    __syncthreads();
    u32 P6 = sP6;
    for (int a = i; a < NA; a += 1024) {
        u32 bits = __float_as_uint(p2[(size_t)b * NA + a].y);
        if (bits >= P6) {
            u32 p = atomicAdd(&nsh, 1u);
            if (p < FBMAX) fbkeys[(size_t)b * FBMAX + p] = ((u64)(~bits) << 32) | (u64)a;
        }
    }
    __syncthreads();
    u32 n = nsh; if (n > FBMAX) n = FBMAX;        // ~6.1K expected; overflow impossible
    volatile u64* vk = (volatile u64*)(fbkeys + (size_t)b * FBMAX);
    for (int i2 = (int)n + i; i2 < FBMAX; i2 += 1024) vk[i2] = ~0ull;
    __syncthreads();
    for (int k = 2; k <= FBMAX; k <<= 1) {        // global-memory bitonic, exact order
        for (int j = k >> 1; j > 0; j >>= 1) {
            for (int p = i; p < FBMAX / 2; p += 1024) {
                int ii = ((p & ~(j - 1)) << 1) | (p & (j - 1));
                int l = ii | j;
                u64 a = vk[ii], c = vk[l];
                bool up = ((ii & k) == 0);
                if ((a > c) == up) { vk[ii] = c; vk[l] = a; }
            }
            __syncthreads();
        }
    }
    int acc_n = 0;
    int limit = (int)n < TOPK ? (int)n : TOPK;
    for (int t = 0; t < limit && acc_n < PROP; ++t) {
        u32 idx = (u32)vk[t];
        float4 bi2; float ai2;
        decode_box(anchors[(size_t)b * NA + idx], bbox[(size_t)b * NA + idx], bi2, ai2);
        int pred = 0;
        if (i < acc_n) pred = sup_pred(bi2, ai2, abox[i], aar[i]) ? 1 : 0;
        int any = __syncthreads_or(pred);
        if (!any) {
            if (i == 0) {
                abox[acc_n] = bi2; aar[acc_n] = ai2;
                out[b * PROP + acc_n] = bi2;
            }
            ++acc_n;
            __syncthreads();
        }
    }
    for (int t = acc_n + i; t < PROP; t += 1024)
        out[b * PROP + t] = make_float4(0.f, 0.f, 0.f, 0.f);
}

// ---------------- launch ----------------------------------------------------

extern "C" void kernel_launch(void* const* d_in, const int* in_sizes, int n_in,
                              void* d_out, int out_size, void* d_ws, size_t ws_size,
                              hipStream_t stream) {
    (void)in_sizes; (void)n_in; (void)out_size;
    if (ws_size < (size_t)WS_NEEDED) return;   // ws_size constant per process -> same work every call
    const float2* p2      = (const float2*)d_in[0];
    const float4* p4      = (const float4*)d_in[0];
    const float4* bbox    = (const float4*)d_in[1];
    const float4* anchors = (const float4*)d_in[2];
    float4* out = (float4*)d_out;

    char* ws = (char*)d_ws;
    u64* fbkeys  = (u64*)(ws + OFF_FBK);
    u64* cache   = (u64*)(ws + OFF_CACHE);
    u32* cnt     = (u32*)(ws + OFF_CNT);
    u32* stat_g  = (u32*)(ws + OFF_STAT);
    float4* boxes= (float4*)(ws + OFF_BOX);
    float* areas = (float*)(ws + OFF_AREA);
    u32* maskT   = (u32*)(ws + OFF_MASK);

    dim3 ghc(SEGS, BATCH), gmask(TOP1 / 4, BATCH);
    k_histcache<<<ghc,   256, 0, stream>>>(p4, cache, cnt);
    k_sortdec  <<<BATCH, 1024, 0, stream>>>(cache, cnt, anchors, bbox, stat_g, boxes, areas);
    k_mask     <<<gmask, 256, 0, stream>>>(boxes, areas, maskT);
    k_nmsfb    <<<BATCH, 1024, 0, stream>>>(maskT, boxes, p2, bbox, anchors, stat_g, fbkeys, out);
}